// Round 5
// baseline (120.476 us; speedup 1.0000x reference)
//
#include <hip/hip_runtime.h>

#define CC 128
#define OO 128
#define HH 64
#define WW 64
#define HW (HH*WW)

typedef __attribute__((ext_vector_type(8))) __bf16 bf16x8;
typedef __attribute__((ext_vector_type(4))) __bf16 bf16x4;
typedef __attribute__((ext_vector_type(4))) float  f32x4;

// ---------------------------------------------------------------------------
// prep (verbatim, passed): BN+ReLU -> h NHWC bf16; weight relayouts into
// MFMA-fragment-swizzled order (wave B-frag load = one contiguous 1KB txn).
// ---------------------------------------------------------------------------
__global__ __launch_bounds__(256) void prep(
    const float* __restrict__ x,
    const float* __restrict__ gamma, const float* __restrict__ beta,
    const float* __restrict__ mean,  const float* __restrict__ var,
    const float* __restrict__ w_dconv, const float* __restrict__ w_off,
    __bf16* __restrict__ h,            // [b][y][x][c]
    __bf16* __restrict__ wt_swz,       // 147456 elems
    __bf16* __restrict__ woff_swz)     // 36864 elems
{
    __shared__ float inv_s[128], bb_s[128];
    __shared__ __bf16 tile[64 * 130];
    int blk = blockIdx.x;
    int tid = threadIdx.x;

    if (blk >= 512) {                  // ---- weight swizzle part ----
        int idx = (blk - 512) * 256 + tid;
        if (idx < 147456) {            // 9kk x 4ks x 8og x 64lane x 8j
            int j    = idx & 7;
            int lane = (idx >> 3) & 63;
            int og   = (idx >> 9) & 7;
            int ks   = (idx >> 12) & 3;
            int kk   = idx >> 14;
            int o = og * 16 + (lane & 15);
            int c = ks * 32 + (lane >> 4) * 8 + j;
            wt_swz[idx] = (__bf16)w_dconv[(o * 128 + c) * 9 + kk];
        }
        if (idx < 36864) {             // 9kk x 4ks x 2og x 64lane x 8j
            int j    = idx & 7;
            int lane = (idx >> 3) & 63;
            int og   = (idx >> 9) & 1;
            int ks   = (idx >> 10) & 3;
            int kk   = idx >> 12;
            int o = og * 16 + (lane & 15);
            int c = ks * 32 + (lane >> 4) * 8 + j;
            float v = (o < 18) ? w_off[o * 1152 + c * 9 + kk] : 0.f;
            woff_swz[idx] = (__bf16)v;
        }
        return;
    }

    // ---- BN+ReLU part ----
    int b = blk & 7, y = blk >> 3;
    if (tid < 128) {
        float iv = gamma[tid] * rsqrtf(var[tid] + 1e-5f);
        inv_s[tid] = iv;
        bb_s[tid]  = beta[tid] - mean[tid] * iv;
    }
    __syncthreads();

    const float* xb = x + (size_t)b * CC * HW + (size_t)y * WW;
    #pragma unroll
    for (int i = 0; i < 8; ++i) {
        int idx = i * 256 + tid;          // 128c x 16 x-quads
        int c = idx >> 4, x4 = idx & 15;
        float4 v = *(const float4*)(xb + (size_t)c * HW + x4 * 4);
        float iv = inv_s[c], bb = bb_s[c];
        tile[(x4 * 4 + 0) * 130 + c] = (__bf16)fmaxf(v.x * iv + bb, 0.f);
        tile[(x4 * 4 + 1) * 130 + c] = (__bf16)fmaxf(v.y * iv + bb, 0.f);
        tile[(x4 * 4 + 2) * 130 + c] = (__bf16)fmaxf(v.z * iv + bb, 0.f);
        tile[(x4 * 4 + 3) * 130 + c] = (__bf16)fmaxf(v.w * iv + bb, 0.f);
    }
    __syncthreads();

    __bf16* hb = h + ((size_t)b * HW + (size_t)y * WW) * CC;
    #pragma unroll
    for (int i = 0; i < 2; ++i) {
        int idx = i * 256 + tid;          // 64x x 8 c16-groups
        int xx = idx >> 3, c16 = idx & 7;
        const uint* src = (const uint*)&tile[xx * 130 + c16 * 16];
        uint r0 = src[0], r1 = src[1], r2 = src[2], r3 = src[3];
        uint r4 = src[4], r5 = src[5], r6 = src[6], r7 = src[7];
        uint* dst = (uint*)(hb + (size_t)xx * CC + c16 * 16);
        *(uint4*)dst       = (uint4){r0, r1, r2, r3};
        *(uint4*)(dst + 4) = (uint4){r4, r5, r6, r7};
    }
}

// ---------------------------------------------------------------------------
// FUSED (R5): half-row blocks. 1024 blocks x 512 threads; each block owns
// (b, y, x-half of 32). LDS 26.6 KB, per-thread state halved (tap regs
// 16 VGPR, staging i=1) => __launch_bounds__(512,6) targets 3 blocks/CU =
// 24 waves/CU (was 16). Per-output numerics bit-identical to R4: same blend
// formula, same kk->ks K-order, bounds on global x. Phase A duplicated
// across wave pairs (identical f32 duplicate stores to offs_lds: benign).
// ---------------------------------------------------------------------------
__global__ __launch_bounds__(512, 6) void fused_mfma(
    const __bf16* __restrict__ h,        // [b][y][x][c] bf16
    const __bf16* __restrict__ woff_swz, // fragment-swizzled offset weights
    const float* __restrict__ b_off,
    const __bf16* __restrict__ wt_swz,   // fragment-swizzled dconv weights
    const float* __restrict__ b_dconv,
    float* __restrict__ out)             // NCHW fp32
{
    __shared__ float pw[288 * 4];        // 4608 B
    __shared__ ushort pidx[288 * 4];     // 2304 B (pixel idx y*64+x)
    __shared__ __align__(16) __bf16 vt[2][32 * 136];  // 17408 B
    __shared__ float offs_lds[18 * 32];  // 2304 B  [oc][xxl]

    int blk = blockIdx.x;                // [0,1024)
    int b  = blk & 7;
    int y  = (blk >> 3) & 63;
    int x0 = (blk >> 9) * 32;            // x-half origin
    int tid = threadIdx.x;
    int lane = tid & 63;
    int wv  = __builtin_amdgcn_readfirstlane(tid >> 6);   // 0..7
    int l15 = lane & 15, quad = lane >> 4;

    int sxx = tid >> 4, sc8 = tid & 15;  // staging: 32 xx x 16 c8 = 512

    const __bf16* hb = h + (size_t)b * HW * CC;

    // ================= phase A: offset conv =================
    {
        const bf16x8* w8 = (const bf16x8*)woff_swz;
        int ma  = wv & 1;         // m-strip (16 x-rows of 32)
        int oga = (wv >> 1) & 1;  // o-16-block (waves 4-7 duplicate 0-3)

        f32x4 acc = (f32x4){0.f, 0.f, 0.f, 0.f};

        uint4 pa;
        // ---- prologue: masked load for kk = 0 (dy=-1, dx=-1) ----
        {
            int yy = y - 1;
            int xs = x0 + sxx - 1;
            pa = (uint4){0u, 0u, 0u, 0u};
            if (yy >= 0 && xs >= 0 && xs < WW)
                pa = *(const uint4*)(hb + ((size_t)yy * WW + xs) * CC + sc8 * 8);
        }

        for (int kk = 0; kk < 9; ++kk) {
            int buf = kk & 1;
            // ---- write staged A from regs ----
            *(uint4*)&vt[buf][sxx * 136 + sc8 * 8] = pa;
            // ---- issue load for kk+1 (flies across the barrier) ----
            if (kk < 8) {
                int k2 = kk + 1;
                int dy = k2 / 3 - 1, dx = k2 % 3 - 1;
                int yy = y + dy;
                int xs = x0 + sxx + dx;
                pa = (uint4){0u, 0u, 0u, 0u};
                if (yy >= 0 && yy < HH && xs >= 0 && xs < WW)
                    pa = *(const uint4*)(hb + ((size_t)yy * WW + xs) * CC + sc8 * 8);
            }
            asm volatile("s_waitcnt lgkmcnt(0)" ::: "memory");  // LDS writes visible
            __builtin_amdgcn_s_barrier();                       // no vmcnt drain
            // ---- MFMA(kk): wave = 16x x 16o ----
            #pragma unroll
            for (int ks = 0; ks < 4; ++ks) {
                int kb = ks * 32 + quad * 8;
                bf16x8 a  = *(const bf16x8*)&vt[buf][(ma * 16 + l15) * 136 + kb];
                bf16x8 b0 = w8[((kk * 4 + ks) * 2 + oga) * 64 + lane];
                acc = __builtin_amdgcn_mfma_f32_16x16x32_bf16(a, b0, acc, 0, 0, 0);
            }
        }

        // ---- epilogue -> LDS (wave pairs write identical values) ----
        {
            int oc = oga * 16 + l15;
            if (oc < 18) {
                float bias = b_off[oc];
                #pragma unroll
                for (int r = 0; r < 4; ++r) {
                    int xxl = ma * 16 + quad * 4 + r;
                    offs_lds[oc * 32 + xxl] = acc[r] + bias;
                }
            }
        }
    }
    __syncthreads();                     // offs_lds visible; vt free for reuse

    // ================= phase 0: bilinear params (from LDS offsets) ========
    if (tid < 288) {
        int e = tid;
        int kk = e >> 5, xxl = e & 31;
        float dy = offs_lds[(2 * kk) * 32 + xxl];
        float dx = offs_lds[(2 * kk + 1) * 32 + xxl];
        float py = dy + (float)y + (float)(kk / 3 - 1);
        float px = dx + (float)(x0 + xxl) + (float)(kk % 3 - 1);
        float fy = floorf(py), fx = floorf(px);
        int y0 = (int)fy, xq0 = (int)fx;
        float wy = py - fy, wx = px - fx;
        int y1 = y0 + 1, xq1 = xq0 + 1;
        bool vy0 = (y0 >= 0) && (y0 < HH);
        bool vy1 = (y1 >= 0) && (y1 < HH);
        bool vx0 = (xq0 >= 0) && (xq0 < WW);
        bool vx1 = (xq1 >= 0) && (xq1 < WW);
        int yc0 = min(max(y0, 0), HH - 1), yc1 = min(max(y1, 0), HH - 1);
        int xc0 = min(max(xq0, 0), WW - 1), xc1 = min(max(xq1, 0), WW - 1);
        pw[e * 4 + 0] = (vy0 && vx0) ? (1.f - wy) * (1.f - wx) : 0.f;
        pw[e * 4 + 1] = (vy0 && vx1) ? (1.f - wy) * wx         : 0.f;
        pw[e * 4 + 2] = (vy1 && vx0) ? wy * (1.f - wx)         : 0.f;
        pw[e * 4 + 3] = (vy1 && vx1) ? wy * wx                 : 0.f;
        pidx[e * 4 + 0] = (ushort)(yc0 * WW + xc0);
        pidx[e * 4 + 1] = (ushort)(yc0 * WW + xc1);
        pidx[e * 4 + 2] = (ushort)(yc1 * WW + xc0);
        pidx[e * 4 + 3] = (ushort)(yc1 * WW + xc1);
    }
    __syncthreads();                     // pw/pidx visible to all

    // ================= phase B: deformable conv =================
    const bf16x8* w8 = (const bf16x8*)wt_swz;

    f32x4 acc[2];
    acc[0] = (f32x4){0.f, 0.f, 0.f, 0.f};
    acc[1] = (f32x4){0.f, 0.f, 0.f, 0.f};

    bf16x8 pt0, pt1, pt2, pt3;
    // ---- prologue: tap loads for kk = 0 ----
    {
        int e = sxx;                     // kk = 0
        pt0 = *(const bf16x8*)(hb + ((int)pidx[e * 4 + 0] << 7) + sc8 * 8);
        pt1 = *(const bf16x8*)(hb + ((int)pidx[e * 4 + 1] << 7) + sc8 * 8);
        pt2 = *(const bf16x8*)(hb + ((int)pidx[e * 4 + 2] << 7) + sc8 * 8);
        pt3 = *(const bf16x8*)(hb + ((int)pidx[e * 4 + 3] << 7) + sc8 * 8);
    }

    for (int kk = 0; kk < 9; ++kk) {
        int buf = kk & 1;
        // ---- blend prefetched taps -> vt[buf] ----
        {
            int e = (kk << 5) + sxx;
            float w0 = pw[e * 4 + 0], w1 = pw[e * 4 + 1];
            float w2 = pw[e * 4 + 2], w3 = pw[e * 4 + 3];
            bf16x8 pk;
            #pragma unroll
            for (int q = 0; q < 8; ++q) {
                float v = w0 * (float)pt0[q] + w1 * (float)pt1[q]
                        + w2 * (float)pt2[q] + w3 * (float)pt3[q];
                pk[q] = (__bf16)v;
            }
            *(bf16x8*)&vt[buf][sxx * 136 + sc8 * 8] = pk;
        }
        // ---- issue tap loads for kk+1 (fly across the barrier) ----
        if (kk < 8) {
            int e2 = ((kk + 1) << 5) + sxx;
            pt0 = *(const bf16x8*)(hb + ((int)pidx[e2 * 4 + 0] << 7) + sc8 * 8);
            pt1 = *(const bf16x8*)(hb + ((int)pidx[e2 * 4 + 1] << 7) + sc8 * 8);
            pt2 = *(const bf16x8*)(hb + ((int)pidx[e2 * 4 + 2] << 7) + sc8 * 8);
            pt3 = *(const bf16x8*)(hb + ((int)pidx[e2 * 4 + 3] << 7) + sc8 * 8);
        }
        asm volatile("s_waitcnt lgkmcnt(0)" ::: "memory");  // LDS writes visible
        __builtin_amdgcn_s_barrier();                       // no vmcnt drain
        // ---- MFMA(kk): 4 K-steps; wave covers 32x x 16o ----
        #pragma unroll
        for (int ks = 0; ks < 4; ++ks) {
            int kb = ks * 32 + quad * 8;
            bf16x8 b0 = w8[((kk * 4 + ks) * 8 + wv) * 64 + lane];
            bf16x8 a0 = *(const bf16x8*)&vt[buf][(0 * 16 + l15) * 136 + kb];
            bf16x8 a1 = *(const bf16x8*)&vt[buf][(1 * 16 + l15) * 136 + kb];
            acc[0] = __builtin_amdgcn_mfma_f32_16x16x32_bf16(a0, b0, acc[0], 0, 0, 0);
            acc[1] = __builtin_amdgcn_mfma_f32_16x16x32_bf16(a1, b0, acc[1], 0, 0, 0);
        }
    }

    // ---- epilogue ----
    size_t ob = (size_t)b * OO * HW + (size_t)y * WW;
    {
        int o = wv * 16 + l15;
        float bias = b_dconv[o];
        #pragma unroll
        for (int mt = 0; mt < 2; ++mt) {
            int xb = x0 + mt * 16 + quad * 4;
            float4 r;
            r.x = acc[mt][0] + bias;
            r.y = acc[mt][1] + bias;
            r.z = acc[mt][2] + bias;
            r.w = acc[mt][3] + bias;
            *(float4*)&out[ob + (size_t)o * HW + xb] = r;
        }
    }
}

// ---------------------------------------------------------------------------
extern "C" void kernel_launch(void* const* d_in, const int* in_sizes, int n_in,
                              void* d_out, int out_size, void* d_ws, size_t ws_size,
                              hipStream_t stream)
{
    const float* x       = (const float*)d_in[0];
    const float* gamma   = (const float*)d_in[1];
    const float* beta    = (const float*)d_in[2];
    const float* mean    = (const float*)d_in[3];
    const float* var     = (const float*)d_in[4];
    const float* w_off   = (const float*)d_in[5];
    const float* b_off   = (const float*)d_in[6];
    const float* w_dconv = (const float*)d_in[7];
    const float* b_dconv = (const float*)d_in[8];
    float* out = (float*)d_out;

    char* ws = (char*)d_ws;
    __bf16* h_bf     = (__bf16*)ws;                 // 8,388,608 B
    __bf16* wt_swz   = (__bf16*)(ws + 8388608);     //   294,912 B
    __bf16* woff_swz = (__bf16*)(ws + 8683520);     //    73,728 B

    prep<<<1232, 256, 0, stream>>>(x, gamma, beta, mean, var,
                                   w_dconv, w_off, h_bf, wt_swz, woff_swz);
    fused_mfma<<<1024, 512, 0, stream>>>(h_bf, woff_swz, b_off,
                                         wt_swz, b_dconv, out);
}

// Round 6
// 116.028 us; speedup vs baseline: 1.0383x; 1.0383x over previous
//
#include <hip/hip_runtime.h>

#define CC 128
#define OO 128
#define HH 64
#define WW 64
#define HW (HH*WW)

typedef __attribute__((ext_vector_type(8))) __bf16 bf16x8;
typedef __attribute__((ext_vector_type(4))) __bf16 bf16x4;
typedef __attribute__((ext_vector_type(4))) float  f32x4;

// ---------------------------------------------------------------------------
// prep (verbatim, passed): BN+ReLU -> h NHWC bf16; weight relayouts into
// MFMA-fragment-swizzled order (wave B-frag load = one contiguous 1KB txn).
// ---------------------------------------------------------------------------
__global__ __launch_bounds__(256) void prep(
    const float* __restrict__ x,
    const float* __restrict__ gamma, const float* __restrict__ beta,
    const float* __restrict__ mean,  const float* __restrict__ var,
    const float* __restrict__ w_dconv, const float* __restrict__ w_off,
    __bf16* __restrict__ h,            // [b][y][x][c]
    __bf16* __restrict__ wt_swz,       // 147456 elems
    __bf16* __restrict__ woff_swz)     // 36864 elems
{
    __shared__ float inv_s[128], bb_s[128];
    __shared__ __bf16 tile[64 * 130];
    int blk = blockIdx.x;
    int tid = threadIdx.x;

    if (blk >= 512) {                  // ---- weight swizzle part ----
        int idx = (blk - 512) * 256 + tid;
        if (idx < 147456) {            // 9kk x 4ks x 8og x 64lane x 8j
            int j    = idx & 7;
            int lane = (idx >> 3) & 63;
            int og   = (idx >> 9) & 7;
            int ks   = (idx >> 12) & 3;
            int kk   = idx >> 14;
            int o = og * 16 + (lane & 15);
            int c = ks * 32 + (lane >> 4) * 8 + j;
            wt_swz[idx] = (__bf16)w_dconv[(o * 128 + c) * 9 + kk];
        }
        if (idx < 36864) {             // 9kk x 4ks x 2og x 64lane x 8j
            int j    = idx & 7;
            int lane = (idx >> 3) & 63;
            int og   = (idx >> 9) & 1;
            int ks   = (idx >> 10) & 3;
            int kk   = idx >> 12;
            int o = og * 16 + (lane & 15);
            int c = ks * 32 + (lane >> 4) * 8 + j;
            float v = (o < 18) ? w_off[o * 1152 + c * 9 + kk] : 0.f;
            woff_swz[idx] = (__bf16)v;
        }
        return;
    }

    // ---- BN+ReLU part ----
    int b = blk & 7, y = blk >> 3;
    if (tid < 128) {
        float iv = gamma[tid] * rsqrtf(var[tid] + 1e-5f);
        inv_s[tid] = iv;
        bb_s[tid]  = beta[tid] - mean[tid] * iv;
    }
    __syncthreads();

    const float* xb = x + (size_t)b * CC * HW + (size_t)y * WW;
    #pragma unroll
    for (int i = 0; i < 8; ++i) {
        int idx = i * 256 + tid;          // 128c x 16 x-quads
        int c = idx >> 4, x4 = idx & 15;
        float4 v = *(const float4*)(xb + (size_t)c * HW + x4 * 4);
        float iv = inv_s[c], bb = bb_s[c];
        tile[(x4 * 4 + 0) * 130 + c] = (__bf16)fmaxf(v.x * iv + bb, 0.f);
        tile[(x4 * 4 + 1) * 130 + c] = (__bf16)fmaxf(v.y * iv + bb, 0.f);
        tile[(x4 * 4 + 2) * 130 + c] = (__bf16)fmaxf(v.z * iv + bb, 0.f);
        tile[(x4 * 4 + 3) * 130 + c] = (__bf16)fmaxf(v.w * iv + bb, 0.f);
    }
    __syncthreads();

    __bf16* hb = h + ((size_t)b * HW + (size_t)y * WW) * CC;
    #pragma unroll
    for (int i = 0; i < 2; ++i) {
        int idx = i * 256 + tid;          // 64x x 8 c16-groups
        int xx = idx >> 3, c16 = idx & 7;
        const uint* src = (const uint*)&tile[xx * 130 + c16 * 16];
        uint r0 = src[0], r1 = src[1], r2 = src[2], r3 = src[3];
        uint r4 = src[4], r5 = src[5], r6 = src[6], r7 = src[7];
        uint* dst = (uint*)(hb + (size_t)xx * CC + c16 * 16);
        *(uint4*)dst       = (uint4){r0, r1, r2, r3};
        *(uint4*)(dst + 4) = (uint4){r4, r5, r6, r7};
    }
}

// ---------------------------------------------------------------------------
// FUSED (R6): R4 base (512 blocks x 512 threads, best so far) with phase A
// restructured: stage the 3-row halo (rows y-1..y+1, x-pad cols zeroed,
// OOB rows zeroed) ONCE into tile3[3][66][136], then run all 36 phase-A
// MFMAs barrier-free, applying the (dy,dx) shift as an LDS address offset.
// Fragment values identical to R4's staged values -> bit-identical output.
// 9 lgkm+barrier pairs -> 1; phase-A L2 traffic 288KB -> 54KB per block.
// Phase B / phase 0 / epilogues verbatim R4. LDS arena 58,464 B, phase B
// reuses dead tile3 region => 2 blocks/CU (16 waves/CU), same as R4.
// ---------------------------------------------------------------------------
__global__ __launch_bounds__(512, 4) void fused_mfma(
    const __bf16* __restrict__ h,        // [b][y][x][c] bf16
    const __bf16* __restrict__ woff_swz, // fragment-swizzled offset weights
    const float* __restrict__ b_off,
    const __bf16* __restrict__ wt_swz,   // fragment-swizzled dconv weights
    const float* __restrict__ b_dconv,
    float* __restrict__ out)             // NCHW fp32
{
    __shared__ __align__(16) char smem[58464];
    // phase A view:
    __bf16* tile3    = (__bf16*)smem;                // [3][66][136] = 53856 B
    float*  offs_lds = (float*)(smem + 53856);       // [18][64] = 4608 B
    // phase B view (tile3 dead after phase A):
    float*  pw   = (float*)smem;                     // [576][4] = 9216 B
    ushort* pidx = (ushort*)(smem + 9216);           // [576][4] = 4608 B
    __bf16* vt   = (__bf16*)(smem + 13824);          // [2][64*136] = 34816 B

    int blk = blockIdx.x;
    int b = blk & 7, y = blk >> 3;
    int tid = threadIdx.x;
    int lane = tid & 63;
    int wv  = __builtin_amdgcn_readfirstlane(tid >> 6);   // 0..7
    int l15 = lane & 15, quad = lane >> 4;

    const __bf16* hb = h + (size_t)b * HW * CC;

    // ================= phase A: offset conv, single-staged halo ===========
    {
        // ---- zero the pad columns (x = -1 and x = 64) of each y-row ----
        if (tid < 96) {                  // 3r x 2col x 16c8
            int r = tid >> 5, col = (tid >> 4) & 1, c8 = tid & 15;
            *(uint4*)&tile3[((r * 66) + (col ? 65 : 0)) * 136 + c8 * 8] =
                (uint4){0u, 0u, 0u, 0u};
        }
        // ---- stage rows y-1..y+1 once (zeros if OOB) ----
        #pragma unroll
        for (int i = 0; i < 6; ++i) {
            int s  = i * 512 + tid;      // 3072 segs: 3r x 64xx x 16c8
            int r  = s >> 10;
            int xx = (s >> 4) & 63;
            int c8 = s & 15;
            int yy = y + r - 1;
            uint4 v = (uint4){0u, 0u, 0u, 0u};
            if (yy >= 0 && yy < HH)
                v = *(const uint4*)(hb + ((size_t)yy * WW + xx) * CC + c8 * 8);
            *(uint4*)&tile3[(r * 66 + xx + 1) * 136 + c8 * 8] = v;
        }
        __syncthreads();

        const bf16x8* w8 = (const bf16x8*)woff_swz;
        int ma  = wv & 3;                // m-strip (16 x-rows)
        int oga = wv >> 2;               // o-16-block (0..1)

        f32x4 acc = (f32x4){0.f, 0.f, 0.f, 0.f};
        #pragma unroll
        for (int kk = 0; kk < 9; ++kk) {
            int dyi = kk / 3, dx = kk % 3 - 1;
            // A-row for this lane: h[y+dyi-1][ma*16+l15+dx] (zeros OOB)
            const __bf16* arow =
                &tile3[(dyi * 66 + ma * 16 + l15 + dx + 1) * 136];
            #pragma unroll
            for (int ks = 0; ks < 4; ++ks) {
                int kb = ks * 32 + quad * 8;
                bf16x8 a  = *(const bf16x8*)&arow[kb];
                bf16x8 b0 = w8[((kk * 4 + ks) * 2 + oga) * 64 + lane];
                acc = __builtin_amdgcn_mfma_f32_16x16x32_bf16(a, b0, acc, 0, 0, 0);
            }
        }

        // ---- epilogue -> LDS ----
        {
            int oc = oga * 16 + l15;
            if (oc < 18) {
                float bias = b_off[oc];
                #pragma unroll
                for (int r = 0; r < 4; ++r) {
                    int xx = ma * 16 + quad * 4 + r;
                    offs_lds[oc * 64 + xx] = acc[r] + bias;
                }
            }
        }
    }
    __syncthreads();                     // offs_lds visible; tile3 now dead

    // ================= phase 0: bilinear params (from LDS offsets) ========
    for (int e = tid; e < 576; e += 512) {
        int kk = e >> 6, xx = e & 63;
        float dy = offs_lds[(2 * kk) * 64 + xx];
        float dx = offs_lds[(2 * kk + 1) * 64 + xx];
        float py = dy + (float)y + (float)(kk / 3 - 1);
        float px = dx + (float)xx + (float)(kk % 3 - 1);
        float fy = floorf(py), fx = floorf(px);
        int y0 = (int)fy, x0 = (int)fx;
        float wy = py - fy, wx = px - fx;
        int y1 = y0 + 1, x1 = x0 + 1;
        bool vy0 = (y0 >= 0) && (y0 < HH);
        bool vy1 = (y1 >= 0) && (y1 < HH);
        bool vx0 = (x0 >= 0) && (x0 < WW);
        bool vx1 = (x1 >= 0) && (x1 < WW);
        int yc0 = min(max(y0, 0), HH - 1), yc1 = min(max(y1, 0), HH - 1);
        int xc0 = min(max(x0, 0), WW - 1), xc1 = min(max(x1, 0), WW - 1);
        pw[e * 4 + 0] = (vy0 && vx0) ? (1.f - wy) * (1.f - wx) : 0.f;
        pw[e * 4 + 1] = (vy0 && vx1) ? (1.f - wy) * wx         : 0.f;
        pw[e * 4 + 2] = (vy1 && vx0) ? wy * (1.f - wx)         : 0.f;
        pw[e * 4 + 3] = (vy1 && vx1) ? wy * wx                 : 0.f;
        pidx[e * 4 + 0] = (ushort)(yc0 * WW + xc0);
        pidx[e * 4 + 1] = (ushort)(yc0 * WW + xc1);
        pidx[e * 4 + 2] = (ushort)(yc1 * WW + xc0);
        pidx[e * 4 + 3] = (ushort)(yc1 * WW + xc1);
    }
    __syncthreads();                     // pw/pidx visible to all

    // ================= phase B: deformable conv (verbatim R4) =============
    const bf16x8* w8 = (const bf16x8*)wt_swz;

    f32x4 acc[4];
    #pragma unroll
    for (int mt = 0; mt < 4; ++mt)
        acc[mt] = (f32x4){0.f, 0.f, 0.f, 0.f};

    bf16x8 pt0[2], pt1[2], pt2[2], pt3[2];
    // ---- prologue: tap loads for kk = 0 ----
    #pragma unroll
    for (int i = 0; i < 2; ++i) {
        int idx = i * 512 + tid;
        int xx = idx >> 4, c8 = idx & 15;
        int e = xx;                      // kk = 0
        pt0[i] = *(const bf16x8*)(hb + ((int)pidx[e * 4 + 0] << 7) + c8 * 8);
        pt1[i] = *(const bf16x8*)(hb + ((int)pidx[e * 4 + 1] << 7) + c8 * 8);
        pt2[i] = *(const bf16x8*)(hb + ((int)pidx[e * 4 + 2] << 7) + c8 * 8);
        pt3[i] = *(const bf16x8*)(hb + ((int)pidx[e * 4 + 3] << 7) + c8 * 8);
    }

    for (int kk = 0; kk < 9; ++kk) {
        __bf16* vtb = vt + (kk & 1) * 8704;
        // ---- blend prefetched taps -> vt[buf] ----
        #pragma unroll
        for (int i = 0; i < 2; ++i) {
            int idx = i * 512 + tid;
            int xx = idx >> 4, c8 = idx & 15;
            int e = (kk << 6) + xx;
            float w0 = pw[e * 4 + 0], w1 = pw[e * 4 + 1];
            float w2 = pw[e * 4 + 2], w3 = pw[e * 4 + 3];
            bf16x8 pk;
            #pragma unroll
            for (int q = 0; q < 8; ++q) {
                float v = w0 * (float)pt0[i][q] + w1 * (float)pt1[i][q]
                        + w2 * (float)pt2[i][q] + w3 * (float)pt3[i][q];
                pk[q] = (__bf16)v;
            }
            *(bf16x8*)&vtb[xx * 136 + c8 * 8] = pk;
        }
        // ---- issue tap loads for kk+1 (fly across the barrier) ----
        if (kk < 8) {
            #pragma unroll
            for (int i = 0; i < 2; ++i) {
                int idx = i * 512 + tid;
                int xx = idx >> 4, c8 = idx & 15;
                int e2 = ((kk + 1) << 6) + xx;
                pt0[i] = *(const bf16x8*)(hb + ((int)pidx[e2 * 4 + 0] << 7) + c8 * 8);
                pt1[i] = *(const bf16x8*)(hb + ((int)pidx[e2 * 4 + 1] << 7) + c8 * 8);
                pt2[i] = *(const bf16x8*)(hb + ((int)pidx[e2 * 4 + 2] << 7) + c8 * 8);
                pt3[i] = *(const bf16x8*)(hb + ((int)pidx[e2 * 4 + 3] << 7) + c8 * 8);
            }
        }
        asm volatile("s_waitcnt lgkmcnt(0)" ::: "memory");  // LDS writes visible
        __builtin_amdgcn_s_barrier();                       // no vmcnt drain
        // ---- MFMA(kk): 4 K-steps; wave covers 64x x 16o ----
        #pragma unroll
        for (int ks = 0; ks < 4; ++ks) {
            int kb = ks * 32 + quad * 8;
            bf16x8 b0 = w8[((kk * 4 + ks) * 8 + wv) * 64 + lane];
            bf16x8 a0 = *(const bf16x8*)&vtb[(0 * 16 + l15) * 136 + kb];
            bf16x8 a1 = *(const bf16x8*)&vtb[(1 * 16 + l15) * 136 + kb];
            bf16x8 a2 = *(const bf16x8*)&vtb[(2 * 16 + l15) * 136 + kb];
            bf16x8 a3 = *(const bf16x8*)&vtb[(3 * 16 + l15) * 136 + kb];
            acc[0] = __builtin_amdgcn_mfma_f32_16x16x32_bf16(a0, b0, acc[0], 0, 0, 0);
            acc[1] = __builtin_amdgcn_mfma_f32_16x16x32_bf16(a1, b0, acc[1], 0, 0, 0);
            acc[2] = __builtin_amdgcn_mfma_f32_16x16x32_bf16(a2, b0, acc[2], 0, 0, 0);
            acc[3] = __builtin_amdgcn_mfma_f32_16x16x32_bf16(a3, b0, acc[3], 0, 0, 0);
        }
    }

    // ---- epilogue (verbatim R4) ----
    size_t ob = (size_t)b * OO * HW + (size_t)y * WW;
    {
        int o = wv * 16 + l15;
        float bias = b_dconv[o];
        #pragma unroll
        for (int mt = 0; mt < 4; ++mt) {
            int xb = mt * 16 + quad * 4;
            float4 r;
            r.x = acc[mt][0] + bias;
            r.y = acc[mt][1] + bias;
            r.z = acc[mt][2] + bias;
            r.w = acc[mt][3] + bias;
            *(float4*)&out[ob + (size_t)o * HW + xb] = r;
        }
    }
}

// ---------------------------------------------------------------------------
extern "C" void kernel_launch(void* const* d_in, const int* in_sizes, int n_in,
                              void* d_out, int out_size, void* d_ws, size_t ws_size,
                              hipStream_t stream)
{
    const float* x       = (const float*)d_in[0];
    const float* gamma   = (const float*)d_in[1];
    const float* beta    = (const float*)d_in[2];
    const float* mean    = (const float*)d_in[3];
    const float* var     = (const float*)d_in[4];
    const float* w_off   = (const float*)d_in[5];
    const float* b_off   = (const float*)d_in[6];
    const float* w_dconv = (const float*)d_in[7];
    const float* b_dconv = (const float*)d_in[8];
    float* out = (float*)d_out;

    char* ws = (char*)d_ws;
    __bf16* h_bf     = (__bf16*)ws;                 // 8,388,608 B
    __bf16* wt_swz   = (__bf16*)(ws + 8388608);     //   294,912 B
    __bf16* woff_swz = (__bf16*)(ws + 8683520);     //    73,728 B

    prep<<<1232, 256, 0, stream>>>(x, gamma, beta, mean, var,
                                   w_dconv, w_off, h_bf, wt_swz, woff_swz);
    fused_mfma<<<512, 512, 0, stream>>>(h_bf, woff_swz, b_off,
                                        wt_swz, b_dconv, out);
}